// Round 14
// baseline (587.241 us; speedup 1.0000x reference)
//
#include <hip/hip_runtime.h>
#include <hip/hip_bf16.h>
#include <math.h>

#define F_IN   128
#define HID    128
#define HEADS  4
#define HC1    (HEADS*HID)   // 512
#define CLASSES 2
#define NEG_SLOPE 0.2f
#define LOG2E 1.44269504088896340736f
#define MNEG  -3.0e38f

#define SCAN_CHUNK 2048
#define PREP_BLOCKS 1088   // ceil((128*128 + 4*128*512)/256)
#define ZERO_BLOCKS 64

typedef __attribute__((ext_vector_type(8))) short short8;
typedef __attribute__((ext_vector_type(4))) float f32x4;
typedef __attribute__((ext_vector_type(2))) float f32x2;

__device__ __forceinline__ f32x2 unpack2(unsigned u) {
    f32x2 r;
    r.x = __uint_as_float(u << 16);
    r.y = __uint_as_float(u & 0xffff0000u);
    return r;
}

// ---------------------------------------------------------------------------
// Dispatch A: weights prep (transpose+bf16, combined layouts) ∥ zero(deg)
// ---------------------------------------------------------------------------
__global__ __launch_bounds__(256) void kA_prep_zero(
    const float* __restrict__ w_in, const float* __restrict__ wl1,
    const float* __restrict__ wr1, const float* __restrict__ wl2,
    const float* __restrict__ wr2,
    __hip_bfloat16* __restrict__ w_inT, __hip_bfloat16* __restrict__ wT1,
    __hip_bfloat16* __restrict__ wT2, int* __restrict__ deg, int N)
{
    int b = blockIdx.x;
    if (b >= PREP_BLOCKS) {
        int i = (b - PREP_BLOCKS) * 256 + threadIdx.x;
        int stride = ZERO_BLOCKS * 256;
        for (; i < N; i += stride) deg[i] = 0;
        return;
    }
    int t = b * 256 + threadIdx.x;
    const int S0 = 128 * 128, S1 = 128 * 512;
    if (t < S0) {
        int n = t / 128, k = t % 128;
        w_inT[t] = __float2bfloat16(w_in[(size_t)k * 128 + n]);
    } else if (t < S0 + S1) {
        int idx = t - S0;
        int n = idx / 128, k = idx % 128;
        wT1[idx] = __float2bfloat16(wl1[(size_t)k * 512 + n]);
    } else if (t < S0 + 2 * S1) {
        int idx = t - S0 - S1;
        int n = idx / 128, k = idx % 128;
        wT1[(size_t)(512 + n) * 128 + k] = __float2bfloat16(wr1[(size_t)k * 512 + n]);
    } else if (t < S0 + 3 * S1) {
        int idx = t - S0 - 2 * S1;
        int n = idx / 512, k = idx % 512;
        wT2[idx] = __float2bfloat16(wl2[(size_t)k * 128 + n]);
    } else if (t < S0 + 4 * S1) {
        int idx = t - S0 - 3 * S1;
        int n = idx / 512, k = idx % 512;
        wT2[(size_t)(128 + n) * 512 + k] = __float2bfloat16(wr2[(size_t)k * 128 + n]);
    }
}

// ---------------------------------------------------------------------------
// Dispatch B: deg histogram
// ---------------------------------------------------------------------------
__global__ void deg_kernel(const int* __restrict__ dst_arr, int* __restrict__ deg,
                           int E, int N) {
    int e = blockIdx.x * blockDim.x + threadIdx.x;
    if (e >= E) return;
    int d = dst_arr[e];
    if ((unsigned)d >= (unsigned)N) d = 0;
    atomicAdd(&deg[d], 1);
}

// ---------------------------------------------------------------------------
// Dispatch C: single-kernel exclusive scan (per-block redundant prefix).
// ---------------------------------------------------------------------------
__global__ __launch_bounds__(256) void scan_kernel(
    const int* __restrict__ deg, int* __restrict__ row,
    int* __restrict__ cursor, int n)
{
    __shared__ int tsum[256];
    int b = blockIdx.x, t = threadIdx.x;

    int pre = b * SCAN_CHUNK;
    int s0 = 0;
    for (int i = t; i < pre; i += 256) s0 += deg[i];
    tsum[t] = s0;
    __syncthreads();
    for (int off = 128; off; off >>= 1) {
        if (t < off) tsum[t] += tsum[t + off];
        __syncthreads();
    }
    int boff = tsum[0];
    __syncthreads();

    int base = b * SCAN_CHUNK + t * 8;
    int local[8];
    int s = 0;
    #pragma unroll
    for (int k = 0; k < 8; ++k) {
        int idx = base + k;
        int v = (idx < n) ? deg[idx] : 0;
        local[k] = s;
        s += v;
    }
    tsum[t] = s;
    __syncthreads();
    for (int off = 1; off < 256; off <<= 1) {
        int v = 0;
        if (t >= off) v = tsum[t - off];
        __syncthreads();
        if (t >= off) tsum[t] += v;
        __syncthreads();
    }
    int texcl = (t == 0) ? 0 : tsum[t - 1];
    #pragma unroll
    for (int k = 0; k < 8; ++k) {
        int idx = base + k;
        if (idx < n) {
            int v = boff + texcl + local[k];
            row[idx] = v;
            cursor[idx] = v;
        }
    }
    if (b == gridDim.x - 1 && t == 0) row[n] = boff + tsum[255];
}

// ---------------------------------------------------------------------------
// Dispatch D: scatter src ids by dst
// ---------------------------------------------------------------------------
__global__ void scatter_kernel(const int* __restrict__ src_arr, const int* __restrict__ dst_arr,
                               int* __restrict__ cursor, int* __restrict__ src_sorted,
                               int E, int N) {
    int e = blockIdx.x * blockDim.x + threadIdx.x;
    if (e >= E) return;
    int s = src_arr[e], d = dst_arr[e];
    if ((unsigned)s >= (unsigned)N) s = 0;
    if ((unsigned)d >= (unsigned)N) d = 0;
    int pos = atomicAdd(&cursor[d], 1);
    src_sorted[pos] = s;
}

// ---------------------------------------------------------------------------
// Dispatch E: merged input+L1 transform (persistent-A). Unchanged from r12.
// ---------------------------------------------------------------------------
__global__ __launch_bounds__(256) void l1_merged_kernel(
    const float* __restrict__ x, const __hip_bfloat16* __restrict__ w_inT,
    const float* __restrict__ b_in, const __hip_bfloat16* __restrict__ wT1,
    __hip_bfloat16* __restrict__ xlr1, int M)
{
    constexpr int LDA = 136, LDB = 72;
    __shared__ __align__(16) short As[128 * LDA];
    __shared__ __align__(16) short Bs[128 * LDB];
    short* Ws = As;

    const int tid  = threadIdx.x;
    const int lane = tid & 63;
    const int wid  = tid >> 6;
    const int wm   = wid >> 1;
    const int wn   = wid & 1;
    const int fr   = lane & 15;
    const int fk   = (lane >> 4) * 8;
    const int row0 = blockIdx.y * 128;

    {
        f32x4 acc[4][4] = {};
        for (int k0 = 0; k0 < 128; k0 += 64) {
            __syncthreads();
            #pragma unroll
            for (int it = 0; it < 4; ++it) {
                int chunk = it * 256 + tid;
                int r = chunk >> 3, c = chunk & 7;
                int gr = row0 + r;
                short8 v = {0, 0, 0, 0, 0, 0, 0, 0};
                if (gr < M) {
                    const float* ap = x + (size_t)gr * 128 + k0 + c * 8;
                    float4 a0 = *(const float4*)ap;
                    float4 a1 = *(const float4*)(ap + 4);
                    __hip_bfloat16 h;
                    h = __float2bfloat16(a0.x); v[0] = *(short*)&h;
                    h = __float2bfloat16(a0.y); v[1] = *(short*)&h;
                    h = __float2bfloat16(a0.z); v[2] = *(short*)&h;
                    h = __float2bfloat16(a0.w); v[3] = *(short*)&h;
                    h = __float2bfloat16(a1.x); v[4] = *(short*)&h;
                    h = __float2bfloat16(a1.y); v[5] = *(short*)&h;
                    h = __float2bfloat16(a1.z); v[6] = *(short*)&h;
                    h = __float2bfloat16(a1.w); v[7] = *(short*)&h;
                }
                *(short8*)(&Bs[r * LDB + c * 8]) = v;
            }
            #pragma unroll
            for (int it = 0; it < 4; ++it) {
                int chunk = it * 256 + tid;
                int n = chunk >> 3, c = chunk & 7;
                short8 v = *(const short8*)((const short*)w_inT + (size_t)n * 128 + k0 + c * 8);
                *(short8*)(&Ws[n * LDB + c * 8]) = v;
            }
            __syncthreads();
            #pragma unroll
            for (int kk = 0; kk < 2; ++kk) {
                short8 af[4], bf[4];
                #pragma unroll
                for (int i = 0; i < 4; ++i)
                    af[i] = *(const short8*)(&Bs[(wm * 64 + i * 16 + fr) * LDB + kk * 32 + fk]);
                #pragma unroll
                for (int j = 0; j < 4; ++j)
                    bf[j] = *(const short8*)(&Ws[(wn * 64 + j * 16 + fr) * LDB + kk * 32 + fk]);
                #pragma unroll
                for (int i = 0; i < 4; ++i)
                    #pragma unroll
                    for (int j = 0; j < 4; ++j)
                        acc[i][j] = __builtin_amdgcn_mfma_f32_16x16x32_bf16(af[i], bf[j], acc[i][j], 0, 0, 0);
            }
        }
        __syncthreads();
        #pragma unroll
        for (int i = 0; i < 4; ++i) {
            #pragma unroll
            for (int j = 0; j < 4; ++j) {
                int col = wn * 64 + j * 16 + fr;
                float bv = b_in[col];
                #pragma unroll
                for (int reg = 0; reg < 4; ++reg) {
                    int r = wm * 64 + i * 16 + (lane >> 4) * 4 + reg;
                    float v = acc[i][j][reg] + bv;
                    v = (v > 0.0f) ? v : expm1f(v);
                    __hip_bfloat16 hb = __float2bfloat16(v);
                    As[r * LDA + col] = *reinterpret_cast<short*>(&hb);
                }
            }
        }
        __syncthreads();
    }

    const int colBase = blockIdx.x * 4;
    for (int ct = 0; ct < 4; ++ct) {
        const int col0 = (colBase + ct) * 128;
        f32x4 acc[4][4] = {};
        for (int k0 = 0; k0 < 128; k0 += 64) {
            __syncthreads();
            #pragma unroll
            for (int it = 0; it < 4; ++it) {
                int chunk = it * 256 + tid;
                int n = chunk >> 3, c = chunk & 7;
                short8 v = *(const short8*)((const short*)wT1 + (size_t)(col0 + n) * 128 + k0 + c * 8);
                *(short8*)(&Bs[n * LDB + c * 8]) = v;
            }
            __syncthreads();
            #pragma unroll
            for (int kk = 0; kk < 2; ++kk) {
                short8 af[4], bf[4];
                #pragma unroll
                for (int i = 0; i < 4; ++i)
                    af[i] = *(const short8*)(&As[(wm * 64 + i * 16 + fr) * LDA + k0 + kk * 32 + fk]);
                #pragma unroll
                for (int j = 0; j < 4; ++j)
                    bf[j] = *(const short8*)(&Bs[(wn * 64 + j * 16 + fr) * LDB + kk * 32 + fk]);
                #pragma unroll
                for (int i = 0; i < 4; ++i)
                    #pragma unroll
                    for (int j = 0; j < 4; ++j)
                        acc[i][j] = __builtin_amdgcn_mfma_f32_16x16x32_bf16(af[i], bf[j], acc[i][j], 0, 0, 0);
            }
        }
        const int crow = row0 + wm * 64;
        const int ccol = col0 + wn * 64;
        #pragma unroll
        for (int i = 0; i < 4; ++i) {
            #pragma unroll
            for (int j = 0; j < 4; ++j) {
                int col = ccol + j * 16 + fr;
                #pragma unroll
                for (int reg = 0; reg < 4; ++reg) {
                    int r = crow + i * 16 + (lane >> 4) * 4 + reg;
                    if (r < M) xlr1[(size_t)r * 1024 + col] = (__hip_bfloat16)acc[i][j][reg];
                }
            }
        }
    }
}

// ---------------------------------------------------------------------------
// Dispatch G: bf16 MFMA GEMM (128x128 tile) — L2 transform. Unchanged.
// ---------------------------------------------------------------------------
template<int ACT, typename OutT>
__global__ __launch_bounds__(256) void mfma_gemm_kernel(
    const __hip_bfloat16* __restrict__ A,
    const __hip_bfloat16* __restrict__ BT,
    const float* __restrict__ bias,
    OutT* __restrict__ C,
    int M, int K, int N)
{
    constexpr int LDA = 72;
    __shared__ __align__(16) short As[128 * LDA];
    __shared__ __align__(16) short Bs[128 * LDA];

    const int tid  = threadIdx.x;
    const int lane = tid & 63;
    const int wid  = tid >> 6;
    const int wm   = wid >> 1;
    const int wn   = wid & 1;
    const int fr   = lane & 15;
    const int fk   = (lane >> 4) * 8;

    const int row0 = blockIdx.y * 128;
    const int col0 = blockIdx.x * 128;

    const short* Ag = (const short*)A;
    const short* Bg = (const short*)BT;

    f32x4 acc[4][4] = {};

    for (int k0 = 0; k0 < K; k0 += 64) {
        #pragma unroll
        for (int it = 0; it < 4; ++it) {
            int chunk = it * 256 + tid;
            int r = chunk >> 3, c = chunk & 7;
            int gr = row0 + r;
            short8 v = {0, 0, 0, 0, 0, 0, 0, 0};
            if (gr < M) v = *(const short8*)(Ag + (size_t)gr * K + k0 + c * 8);
            *(short8*)(&As[r * LDA + c * 8]) = v;
        }
        #pragma unroll
        for (int it = 0; it < 4; ++it) {
            int chunk = it * 256 + tid;
            int n = chunk >> 3, c = chunk & 7;
            short8 v = *(const short8*)(Bg + (size_t)(col0 + n) * K + k0 + c * 8);
            *(short8*)(&Bs[n * LDA + c * 8]) = v;
        }
        __syncthreads();
        #pragma unroll
        for (int kk = 0; kk < 2; ++kk) {
            short8 af[4], bf[4];
            #pragma unroll
            for (int i = 0; i < 4; ++i)
                af[i] = *(const short8*)(&As[(wm * 64 + i * 16 + fr) * LDA + kk * 32 + fk]);
            #pragma unroll
            for (int j = 0; j < 4; ++j)
                bf[j] = *(const short8*)(&Bs[(wn * 64 + j * 16 + fr) * LDA + kk * 32 + fk]);
            #pragma unroll
            for (int i = 0; i < 4; ++i)
                #pragma unroll
                for (int j = 0; j < 4; ++j)
                    acc[i][j] = __builtin_amdgcn_mfma_f32_16x16x32_bf16(af[i], bf[j], acc[i][j], 0, 0, 0);
        }
        __syncthreads();
    }

    const int crow = row0 + wm * 64;
    const int ccol = col0 + wn * 64;
    #pragma unroll
    for (int i = 0; i < 4; ++i) {
        #pragma unroll
        for (int j = 0; j < 4; ++j) {
            int col = ccol + j * 16 + (lane & 15);
            float bv = bias ? bias[col] : 0.0f;
            #pragma unroll
            for (int reg = 0; reg < 4; ++reg) {
                int r = crow + i * 16 + (lane >> 4) * 4 + reg;
                if (r < M) {
                    float v = acc[i][j][reg] + bv;
                    if (ACT == 1) v = (v > 0.0f) ? v : expm1f(v);
                    C[(size_t)r * N + col] = (OutT)v;
                }
            }
        }
    }
}

// ---------------------------------------------------------------------------
// Dispatch F: fused GATv2 layer 1 — r12 math, 4-DEEP gather prefetch.
// Named registers a0..a3 (no runtime-indexed arrays -> no scratch).
// Refill conditions are wave-uniform. Virtual list: 0=self, i>=1 -> CSR.
// ---------------------------------------------------------------------------
__global__ __launch_bounds__(256) void gatv2_l1_fused_kernel(
    const __hip_bfloat16* __restrict__ xlr,
    const int* __restrict__ row, const int* __restrict__ src_sorted,
    const float* __restrict__ att, const float* __restrict__ b1,
    __hip_bfloat16* __restrict__ out1, int N)
{
    int d = blockIdx.x * 4 + (threadIdx.x >> 6);
    if (d >= N) return;
    int lane = threadIdx.x & 63;
    int cbase = lane * 8;
    const short* basep = (const short*)xlr;

    f32x2 xrd2[4], attv2[4];
    {
        uint4 raw = *reinterpret_cast<const uint4*>(basep + (size_t)d * 1024 + 512 + cbase);
        const unsigned* u = reinterpret_cast<const unsigned*>(&raw);
        #pragma unroll
        for (int j = 0; j < 4; ++j) xrd2[j] = unpack2(u[j]);
        #pragma unroll
        for (int j = 0; j < 4; ++j) {
            attv2[j].x = att[cbase + 2 * j] * LOG2E;
            attv2[j].y = att[cbase + 2 * j + 1] * LOG2E;
        }
    }

    float m = MNEG;
    float s = 0.0f;
    f32x2 o2[4] = {};

    int rs = row[d], re = row[d + 1];
    int L = re - rs + 1;    // virtual list length

    // edge -> gather address helper
    auto srcrow = [&](int i) -> const uint4* {
        int sn = (i == 0) ? d : src_sorted[rs + i - 1];
        return reinterpret_cast<const uint4*>(basep + (size_t)sn * 1024 + cbase);
    };

    // process one staged row
    auto process = [&](uint4 cur) {
        const unsigned* u = reinterpret_cast<const unsigned*>(&cur);
        f32x2 v2[4];
        #pragma unroll
        for (int j = 0; j < 4; ++j) v2[j] = unpack2(u[j]);

        f32x2 tacc = {0.0f, 0.0f};
        #pragma unroll
        for (int j = 0; j < 4; ++j) {
            f32x2 e = v2[j] + xrd2[j];
            f32x2 ne = e * NEG_SLOPE;
            e.x = fmaxf(e.x, ne.x);
            e.y = fmaxf(e.y, ne.y);
            tacc = __builtin_elementwise_fma(e, attv2[j], tacc);
        }
        float t = tacc.x + tacc.y;
        t += __shfl_xor(t, 1);
        t += __shfl_xor(t, 2);
        t += __shfl_xor(t, 4);
        t += __shfl_xor(t, 8);
        if (t > m) {
            float r = exp2f(m - t);
            s *= r;
            f32x2 r2 = {r, r};
            #pragma unroll
            for (int j = 0; j < 4; ++j) o2[j] *= r2;
            m = t;
        }
        float p = exp2f(t - m);
        s += p;
        f32x2 p2 = {p, p};
        #pragma unroll
        for (int j = 0; j < 4; ++j) o2[j] = __builtin_elementwise_fma(p2, v2[j], o2[j]);
    };

    // 4-deep prefetch pipeline with named registers
    uint4 a0, a1, a2, a3;
    a0 = *srcrow(0);
    if (L > 1) a1 = *srcrow(1);
    if (L > 2) a2 = *srcrow(2);
    if (L > 3) a3 = *srcrow(3);

    int p0 = 0;
    for (; p0 + 4 <= L; p0 += 4) {
        process(a0); if (p0 + 4 < L) a0 = *srcrow(p0 + 4);
        process(a1); if (p0 + 5 < L) a1 = *srcrow(p0 + 5);
        process(a2); if (p0 + 6 < L) a2 = *srcrow(p0 + 6);
        process(a3); if (p0 + 7 < L) a3 = *srcrow(p0 + 7);
    }
    if (p0 < L)     process(a0);
    if (p0 + 1 < L) process(a1);
    if (p0 + 2 < L) process(a2);

    float inv = 1.0f / (s + 1e-16f);
    short8 sv;
    #pragma unroll
    for (int j = 0; j < 4; ++j) {
        #pragma unroll
        for (int h = 0; h < 2; ++h) {
            float val = ((h == 0) ? o2[j].x : o2[j].y) * inv + b1[cbase + 2 * j + h];
            val = (val > 0.0f) ? val : expm1f(val);
            __hip_bfloat16 hb = __float2bfloat16(val);
            sv[2 * j + h] = *reinterpret_cast<short*>(&hb);
        }
    }
    *(short8*)((short*)out1 + (size_t)d * HC1 + cbase) = sv;
}

// ---------------------------------------------------------------------------
// Dispatch H: fused GATv2 layer 2 + classifier + log_softmax. Unchanged (r13).
// ---------------------------------------------------------------------------
__global__ __launch_bounds__(256) void gatv2_l2_final_kernel(
    const __hip_bfloat16* __restrict__ xlr2,
    const int* __restrict__ row, const int* __restrict__ src_sorted,
    const float* __restrict__ att2, const float* __restrict__ b2,
    const float* __restrict__ w_out, const float* __restrict__ b_out,
    float* __restrict__ out, int N)
{
    int d = blockIdx.x * 4 + (threadIdx.x >> 6);
    if (d >= N) return;
    int lane = threadIdx.x & 63;
    int g  = lane >> 4;
    int gl = lane & 15;
    int cbase = gl * 8;
    const short* basep = (const short*)xlr2;

    f32x2 xrd2[4], attv2[4];
    {
        uint4 rawx = *reinterpret_cast<const uint4*>(basep + (size_t)d * 256 + 128 + cbase);
        const unsigned* u = reinterpret_cast<const unsigned*>(&rawx);
        #pragma unroll
        for (int j = 0; j < 4; ++j) xrd2[j] = unpack2(u[j]);
        #pragma unroll
        for (int j = 0; j < 4; ++j) {
            attv2[j].x = att2[cbase + 2 * j] * LOG2E;
            attv2[j].y = att2[cbase + 2 * j + 1] * LOG2E;
        }
    }

    float m = MNEG;
    float s = 0.0f;
    f32x2 o2[4] = {};

    int rs = row[d], re = row[d + 1];
    int L = re - rs + 1;

    uint4 r0;
    if (g < L) {
        int sn = (g == 0) ? d : src_sorted[rs + g - 1];
        r0 = *reinterpret_cast<const uint4*>(basep + (size_t)sn * 256 + cbase);
    }
    for (int p0 = g; p0 < L; p0 += 4) {
        uint4 cur = r0;
        if (p0 + 4 < L) {
            int sn = src_sorted[rs + p0 + 3];
            r0 = *reinterpret_cast<const uint4*>(basep + (size_t)sn * 256 + cbase);
        }
        const unsigned* u = reinterpret_cast<const unsigned*>(&cur);
        f32x2 v2[4];
        #pragma unroll
        for (int j = 0; j < 4; ++j) v2[j] = unpack2(u[j]);

        f32x2 tacc = {0.0f, 0.0f};
        #pragma unroll
        for (int j = 0; j < 4; ++j) {
            f32x2 e = v2[j] + xrd2[j];
            f32x2 ne = e * NEG_SLOPE;
            e.x = fmaxf(e.x, ne.x);
            e.y = fmaxf(e.y, ne.y);
            tacc = __builtin_elementwise_fma(e, attv2[j], tacc);
        }
        float t = tacc.x + tacc.y;
        t += __shfl_xor(t, 1);
        t += __shfl_xor(t, 2);
        t += __shfl_xor(t, 4);
        t += __shfl_xor(t, 8);
        if (t > m) {
            float r = exp2f(m - t);
            s *= r;
            f32x2 r2 = {r, r};
            #pragma unroll
            for (int j = 0; j < 4; ++j) o2[j] *= r2;
            m = t;
        }
        float p = exp2f(t - m);
        s += p;
        f32x2 p2 = {p, p};
        #pragma unroll
        for (int j = 0; j < 4; ++j) o2[j] = __builtin_elementwise_fma(p2, v2[j], o2[j]);
    }

    #pragma unroll
    for (int off = 16; off <= 32; off <<= 1) {
        float m_o = __shfl_xor(m, off);
        float s_o = __shfl_xor(s, off);
        f32x2 oo[4];
        #pragma unroll
        for (int j = 0; j < 4; ++j) {
            oo[j].x = __shfl_xor(o2[j].x, off);
            oo[j].y = __shfl_xor(o2[j].y, off);
        }
        float mn = fmaxf(m, m_o);
        float a = exp2f(m - mn);
        float b = exp2f(m_o - mn);
        s = s * a + s_o * b;
        f32x2 a2 = {a, a}, b2v = {b, b};
        #pragma unroll
        for (int j = 0; j < 4; ++j)
            o2[j] = o2[j] * a2 + oo[j] * b2v;
        m = mn;
    }

    float inv = 1.0f / (s + 1e-16f);
    float a0 = 0.0f, a1 = 0.0f;
    #pragma unroll
    for (int j = 0; j < 4; ++j) {
        #pragma unroll
        for (int h = 0; h < 2; ++h) {
            int c = cbase + 2 * j + h;
            float val = ((h == 0) ? o2[j].x : o2[j].y) * inv + b2[c];
            val = (val > 0.0f) ? val : expm1f(val);
            a0 = fmaf(val, w_out[c * 2 + 0], a0);
            a1 = fmaf(val, w_out[c * 2 + 1], a1);
        }
    }
    #pragma unroll
    for (int off = 1; off <= 8; off <<= 1) {
        a0 += __shfl_xor(a0, off);
        a1 += __shfl_xor(a1, off);
    }
    if (lane == 0) {
        float z0 = a0 + b_out[0];
        float z1 = a1 + b_out[1];
        float mx = fmaxf(z0, z1);
        float lse = mx + logf(__expf(z0 - mx) + __expf(z1 - mx));
        out[(size_t)d * CLASSES + 0] = z0 - lse;
        out[(size_t)d * CLASSES + 1] = z1 - lse;
    }
}

// ---------------------------------------------------------------------------
// launch — 8 dispatches
// ---------------------------------------------------------------------------
extern "C" void kernel_launch(void* const* d_in, const int* in_sizes, int n_in,
                              void* d_out, int out_size, void* d_ws, size_t ws_size,
                              hipStream_t stream)
{
    const float* x     = (const float*)d_in[0];
    const int*   eidx  = (const int*)d_in[1];
    const float* w_in  = (const float*)d_in[2];
    const float* b_in  = (const float*)d_in[3];
    const float* wl1   = (const float*)d_in[4];
    const float* wr1   = (const float*)d_in[5];
    const float* att1  = (const float*)d_in[6];
    const float* b1    = (const float*)d_in[7];
    const float* wl2   = (const float*)d_in[8];
    const float* wr2   = (const float*)d_in[9];
    const float* att2  = (const float*)d_in[10];
    const float* b2    = (const float*)d_in[11];
    const float* w_out = (const float*)d_in[12];
    const float* b_out = (const float*)d_in[13];
    float* out = (float*)d_out;

    const int N = in_sizes[0] / F_IN;      // 50000
    const int E = in_sizes[1] / 2;         // 800000
    const int* src_arr = eidx;
    const int* dst_arr = eidx + E;

    // ---- workspace layout (peak ~160 MB) ----
    size_t off = 0;
    auto alloc = [&](size_t bytes) -> char* {
        char* ptr = (char*)d_ws + off;
        off += (bytes + 255) & ~(size_t)255;
        return ptr;
    };
    int* row        = (int*)alloc((size_t)(N + 1) * 4);
    int* cursor     = (int*)alloc((size_t)N * 4);
    int* deg        = (int*)alloc((size_t)N * 4);
    int* src_sorted = (int*)alloc((size_t)E * 4);
    __hip_bfloat16* w_inT = (__hip_bfloat16*)alloc((size_t)F_IN * HID * 2);
    __hip_bfloat16* wT1   = (__hip_bfloat16*)alloc((size_t)2 * HC1 * HID * 2);  // [1024][128]
    __hip_bfloat16* wT2   = (__hip_bfloat16*)alloc((size_t)2 * HID * HC1 * 2);  // [256][512]
    __hip_bfloat16* xlr1  = (__hip_bfloat16*)alloc((size_t)N * 2 * HC1 * 2);    // [N][1024]
    __hip_bfloat16* out1  = (__hip_bfloat16*)alloc((size_t)N * HC1 * 2);

    __hip_bfloat16* xlr2 = xlr1;   // [N][256] overlays xlr1 (dead after fused L1)

    dim3 blk(256);
    const int NB_SCAN = (N + SCAN_CHUNK - 1) / SCAN_CHUNK;   // 25
    const int nRowBlk = (N + 127) / 128;                     // 391

    // A: weights prep ∥ zero(deg)
    hipLaunchKernelGGL(kA_prep_zero, dim3(PREP_BLOCKS + ZERO_BLOCKS), blk, 0, stream,
                       w_in, wl1, wr1, wl2, wr2, w_inT, wT1, wT2, deg, N);
    // B: deg histogram
    hipLaunchKernelGGL(deg_kernel, dim3((E + 255) / 256), blk, 0, stream, dst_arr, deg, E, N);
    // C: single-kernel scan
    hipLaunchKernelGGL(scan_kernel, dim3(NB_SCAN), blk, 0, stream, deg, row, cursor, N);
    // D: scatter
    hipLaunchKernelGGL(scatter_kernel, dim3((E + 255) / 256), blk, 0, stream,
                       src_arr, dst_arr, cursor, src_sorted, E, N);
    // E: merged input+L1 transform
    {
        dim3 grid(2, nRowBlk);
        hipLaunchKernelGGL(l1_merged_kernel, grid, blk, 0, stream,
                           x, w_inT, b_in, wT1, xlr1, N);
    }
    // F: fused layer 1 (4-deep prefetch)
    hipLaunchKernelGGL(gatv2_l1_fused_kernel, dim3((N + 3) / 4), blk, 0, stream,
                       xlr1, row, src_sorted, att1, b1, out1, N);
    // G: layer 2 transform
    {
        dim3 grid(2 * HID / 128, nRowBlk);
        hipLaunchKernelGGL((mfma_gemm_kernel<0, __hip_bfloat16>), grid, blk, 0, stream,
                           out1, wT2, (const float*)nullptr, xlr2, N, HC1, 2 * HID);
    }
    // H: fused layer 2 + classifier + log_softmax
    hipLaunchKernelGGL(gatv2_l2_final_kernel, dim3((N + 3) / 4), blk, 0, stream,
                       xlr2, row, src_sorted, att2, b2, w_out, b_out, out, N);
}

// Round 15
// 550.452 us; speedup vs baseline: 1.0668x; 1.0668x over previous
//
#include <hip/hip_runtime.h>
#include <hip/hip_bf16.h>
#include <math.h>

#define F_IN   128
#define HID    128
#define HEADS  4
#define HC1    (HEADS*HID)   // 512
#define CLASSES 2
#define NEG_SLOPE 0.2f
#define LOG2E 1.44269504088896340736f
#define MNEG  -3.0e38f

#define SCAN_CHUNK 2048
#define PREP_BLOCKS 1088   // ceil((128*128 + 4*128*512)/256)
#define ZERO_BLOCKS 64

typedef __attribute__((ext_vector_type(8))) short short8;
typedef __attribute__((ext_vector_type(4))) float f32x4;
typedef __attribute__((ext_vector_type(2))) float f32x2;

__device__ __forceinline__ f32x2 unpack2(unsigned u) {
    f32x2 r;
    r.x = __uint_as_float(u << 16);
    r.y = __uint_as_float(u & 0xffff0000u);
    return r;
}

// ---------------------------------------------------------------------------
// Dispatch A: weights prep (transpose+bf16, combined layouts) ∥ zero(deg)
// ---------------------------------------------------------------------------
__global__ __launch_bounds__(256) void kA_prep_zero(
    const float* __restrict__ w_in, const float* __restrict__ wl1,
    const float* __restrict__ wr1, const float* __restrict__ wl2,
    const float* __restrict__ wr2,
    __hip_bfloat16* __restrict__ w_inT, __hip_bfloat16* __restrict__ wT1,
    __hip_bfloat16* __restrict__ wT2, int* __restrict__ deg, int N)
{
    int b = blockIdx.x;
    if (b >= PREP_BLOCKS) {
        int i = (b - PREP_BLOCKS) * 256 + threadIdx.x;
        int stride = ZERO_BLOCKS * 256;
        for (; i < N; i += stride) deg[i] = 0;
        return;
    }
    int t = b * 256 + threadIdx.x;
    const int S0 = 128 * 128, S1 = 128 * 512;
    if (t < S0) {
        int n = t / 128, k = t % 128;
        w_inT[t] = __float2bfloat16(w_in[(size_t)k * 128 + n]);
    } else if (t < S0 + S1) {
        int idx = t - S0;
        int n = idx / 128, k = idx % 128;
        wT1[idx] = __float2bfloat16(wl1[(size_t)k * 512 + n]);
    } else if (t < S0 + 2 * S1) {
        int idx = t - S0 - S1;
        int n = idx / 128, k = idx % 128;
        wT1[(size_t)(512 + n) * 128 + k] = __float2bfloat16(wr1[(size_t)k * 512 + n]);
    } else if (t < S0 + 3 * S1) {
        int idx = t - S0 - 2 * S1;
        int n = idx / 512, k = idx % 512;
        wT2[idx] = __float2bfloat16(wl2[(size_t)k * 128 + n]);
    } else if (t < S0 + 4 * S1) {
        int idx = t - S0 - 3 * S1;
        int n = idx / 512, k = idx % 512;
        wT2[(size_t)(128 + n) * 512 + k] = __float2bfloat16(wr2[(size_t)k * 128 + n]);
    }
}

// ---------------------------------------------------------------------------
// Dispatch B: deg histogram
// ---------------------------------------------------------------------------
__global__ void deg_kernel(const int* __restrict__ dst_arr, int* __restrict__ deg,
                           int E, int N) {
    int e = blockIdx.x * blockDim.x + threadIdx.x;
    if (e >= E) return;
    int d = dst_arr[e];
    if ((unsigned)d >= (unsigned)N) d = 0;
    atomicAdd(&deg[d], 1);
}

// ---------------------------------------------------------------------------
// Dispatch C: single-kernel exclusive scan (per-block redundant prefix).
// ---------------------------------------------------------------------------
__global__ __launch_bounds__(256) void scan_kernel(
    const int* __restrict__ deg, int* __restrict__ row,
    int* __restrict__ cursor, int n)
{
    __shared__ int tsum[256];
    int b = blockIdx.x, t = threadIdx.x;

    int pre = b * SCAN_CHUNK;
    int s0 = 0;
    for (int i = t; i < pre; i += 256) s0 += deg[i];
    tsum[t] = s0;
    __syncthreads();
    for (int off = 128; off; off >>= 1) {
        if (t < off) tsum[t] += tsum[t + off];
        __syncthreads();
    }
    int boff = tsum[0];
    __syncthreads();

    int base = b * SCAN_CHUNK + t * 8;
    int local[8];
    int s = 0;
    #pragma unroll
    for (int k = 0; k < 8; ++k) {
        int idx = base + k;
        int v = (idx < n) ? deg[idx] : 0;
        local[k] = s;
        s += v;
    }
    tsum[t] = s;
    __syncthreads();
    for (int off = 1; off < 256; off <<= 1) {
        int v = 0;
        if (t >= off) v = tsum[t - off];
        __syncthreads();
        if (t >= off) tsum[t] += v;
        __syncthreads();
    }
    int texcl = (t == 0) ? 0 : tsum[t - 1];
    #pragma unroll
    for (int k = 0; k < 8; ++k) {
        int idx = base + k;
        if (idx < n) {
            int v = boff + texcl + local[k];
            row[idx] = v;
            cursor[idx] = v;
        }
    }
    if (b == gridDim.x - 1 && t == 0) row[n] = boff + tsum[255];
}

// ---------------------------------------------------------------------------
// Dispatch D: scatter src ids by dst
// ---------------------------------------------------------------------------
__global__ void scatter_kernel(const int* __restrict__ src_arr, const int* __restrict__ dst_arr,
                               int* __restrict__ cursor, int* __restrict__ src_sorted,
                               int E, int N) {
    int e = blockIdx.x * blockDim.x + threadIdx.x;
    if (e >= E) return;
    int s = src_arr[e], d = dst_arr[e];
    if ((unsigned)s >= (unsigned)N) s = 0;
    if ((unsigned)d >= (unsigned)N) d = 0;
    int pos = atomicAdd(&cursor[d], 1);
    src_sorted[pos] = s;
}

// ---------------------------------------------------------------------------
// Dispatch E: merged input+L1 transform (persistent-A).
// Phase 1: h = elu(x @ w_inT^T + b_in) computed into LDS (bf16, [128][136]).
// Phase 2: 4 col-tiles of xlr1 = h @ wT1^T using the LDS h-tile as A.
// ---------------------------------------------------------------------------
__global__ __launch_bounds__(256) void l1_merged_kernel(
    const float* __restrict__ x, const __hip_bfloat16* __restrict__ w_inT,
    const float* __restrict__ b_in, const __hip_bfloat16* __restrict__ wT1,
    __hip_bfloat16* __restrict__ xlr1, int M)
{
    constexpr int LDA = 136, LDB = 72;
    __shared__ __align__(16) short As[128 * LDA];
    __shared__ __align__(16) short Bs[128 * LDB];
    short* Ws = As;

    const int tid  = threadIdx.x;
    const int lane = tid & 63;
    const int wid  = tid >> 6;
    const int wm   = wid >> 1;
    const int wn   = wid & 1;
    const int fr   = lane & 15;
    const int fk   = (lane >> 4) * 8;
    const int row0 = blockIdx.y * 128;

    {
        f32x4 acc[4][4] = {};
        for (int k0 = 0; k0 < 128; k0 += 64) {
            __syncthreads();
            #pragma unroll
            for (int it = 0; it < 4; ++it) {
                int chunk = it * 256 + tid;
                int r = chunk >> 3, c = chunk & 7;
                int gr = row0 + r;
                short8 v = {0, 0, 0, 0, 0, 0, 0, 0};
                if (gr < M) {
                    const float* ap = x + (size_t)gr * 128 + k0 + c * 8;
                    float4 a0 = *(const float4*)ap;
                    float4 a1 = *(const float4*)(ap + 4);
                    __hip_bfloat16 h;
                    h = __float2bfloat16(a0.x); v[0] = *(short*)&h;
                    h = __float2bfloat16(a0.y); v[1] = *(short*)&h;
                    h = __float2bfloat16(a0.z); v[2] = *(short*)&h;
                    h = __float2bfloat16(a0.w); v[3] = *(short*)&h;
                    h = __float2bfloat16(a1.x); v[4] = *(short*)&h;
                    h = __float2bfloat16(a1.y); v[5] = *(short*)&h;
                    h = __float2bfloat16(a1.z); v[6] = *(short*)&h;
                    h = __float2bfloat16(a1.w); v[7] = *(short*)&h;
                }
                *(short8*)(&Bs[r * LDB + c * 8]) = v;
            }
            #pragma unroll
            for (int it = 0; it < 4; ++it) {
                int chunk = it * 256 + tid;
                int n = chunk >> 3, c = chunk & 7;
                short8 v = *(const short8*)((const short*)w_inT + (size_t)n * 128 + k0 + c * 8);
                *(short8*)(&Ws[n * LDB + c * 8]) = v;
            }
            __syncthreads();
            #pragma unroll
            for (int kk = 0; kk < 2; ++kk) {
                short8 af[4], bf[4];
                #pragma unroll
                for (int i = 0; i < 4; ++i)
                    af[i] = *(const short8*)(&Bs[(wm * 64 + i * 16 + fr) * LDB + kk * 32 + fk]);
                #pragma unroll
                for (int j = 0; j < 4; ++j)
                    bf[j] = *(const short8*)(&Ws[(wn * 64 + j * 16 + fr) * LDB + kk * 32 + fk]);
                #pragma unroll
                for (int i = 0; i < 4; ++i)
                    #pragma unroll
                    for (int j = 0; j < 4; ++j)
                        acc[i][j] = __builtin_amdgcn_mfma_f32_16x16x32_bf16(af[i], bf[j], acc[i][j], 0, 0, 0);
            }
        }
        __syncthreads();
        #pragma unroll
        for (int i = 0; i < 4; ++i) {
            #pragma unroll
            for (int j = 0; j < 4; ++j) {
                int col = wn * 64 + j * 16 + fr;
                float bv = b_in[col];
                #pragma unroll
                for (int reg = 0; reg < 4; ++reg) {
                    int r = wm * 64 + i * 16 + (lane >> 4) * 4 + reg;
                    float v = acc[i][j][reg] + bv;
                    v = (v > 0.0f) ? v : expm1f(v);
                    __hip_bfloat16 hb = __float2bfloat16(v);
                    As[r * LDA + col] = *reinterpret_cast<short*>(&hb);
                }
            }
        }
        __syncthreads();
    }

    const int colBase = blockIdx.x * 4;
    for (int ct = 0; ct < 4; ++ct) {
        const int col0 = (colBase + ct) * 128;
        f32x4 acc[4][4] = {};
        for (int k0 = 0; k0 < 128; k0 += 64) {
            __syncthreads();
            #pragma unroll
            for (int it = 0; it < 4; ++it) {
                int chunk = it * 256 + tid;
                int n = chunk >> 3, c = chunk & 7;
                short8 v = *(const short8*)((const short*)wT1 + (size_t)(col0 + n) * 128 + k0 + c * 8);
                *(short8*)(&Bs[n * LDB + c * 8]) = v;
            }
            __syncthreads();
            #pragma unroll
            for (int kk = 0; kk < 2; ++kk) {
                short8 af[4], bf[4];
                #pragma unroll
                for (int i = 0; i < 4; ++i)
                    af[i] = *(const short8*)(&As[(wm * 64 + i * 16 + fr) * LDA + k0 + kk * 32 + fk]);
                #pragma unroll
                for (int j = 0; j < 4; ++j)
                    bf[j] = *(const short8*)(&Bs[(wn * 64 + j * 16 + fr) * LDB + kk * 32 + fk]);
                #pragma unroll
                for (int i = 0; i < 4; ++i)
                    #pragma unroll
                    for (int j = 0; j < 4; ++j)
                        acc[i][j] = __builtin_amdgcn_mfma_f32_16x16x32_bf16(af[i], bf[j], acc[i][j], 0, 0, 0);
            }
        }
        const int crow = row0 + wm * 64;
        const int ccol = col0 + wn * 64;
        #pragma unroll
        for (int i = 0; i < 4; ++i) {
            #pragma unroll
            for (int j = 0; j < 4; ++j) {
                int col = ccol + j * 16 + fr;
                #pragma unroll
                for (int reg = 0; reg < 4; ++reg) {
                    int r = crow + i * 16 + (lane >> 4) * 4 + reg;
                    if (r < M) xlr1[(size_t)r * 1024 + col] = (__hip_bfloat16)acc[i][j][reg];
                }
            }
        }
    }
}

// ---------------------------------------------------------------------------
// Dispatch G: bf16 MFMA GEMM (128x128 tile) — L2 transform.
// ---------------------------------------------------------------------------
template<int ACT, typename OutT>
__global__ __launch_bounds__(256) void mfma_gemm_kernel(
    const __hip_bfloat16* __restrict__ A,
    const __hip_bfloat16* __restrict__ BT,
    const float* __restrict__ bias,
    OutT* __restrict__ C,
    int M, int K, int N)
{
    constexpr int LDA = 72;
    __shared__ __align__(16) short As[128 * LDA];
    __shared__ __align__(16) short Bs[128 * LDA];

    const int tid  = threadIdx.x;
    const int lane = tid & 63;
    const int wid  = tid >> 6;
    const int wm   = wid >> 1;
    const int wn   = wid & 1;
    const int fr   = lane & 15;
    const int fk   = (lane >> 4) * 8;

    const int row0 = blockIdx.y * 128;
    const int col0 = blockIdx.x * 128;

    const short* Ag = (const short*)A;
    const short* Bg = (const short*)BT;

    f32x4 acc[4][4] = {};

    for (int k0 = 0; k0 < K; k0 += 64) {
        #pragma unroll
        for (int it = 0; it < 4; ++it) {
            int chunk = it * 256 + tid;
            int r = chunk >> 3, c = chunk & 7;
            int gr = row0 + r;
            short8 v = {0, 0, 0, 0, 0, 0, 0, 0};
            if (gr < M) v = *(const short8*)(Ag + (size_t)gr * K + k0 + c * 8);
            *(short8*)(&As[r * LDA + c * 8]) = v;
        }
        #pragma unroll
        for (int it = 0; it < 4; ++it) {
            int chunk = it * 256 + tid;
            int n = chunk >> 3, c = chunk & 7;
            short8 v = *(const short8*)(Bg + (size_t)(col0 + n) * K + k0 + c * 8);
            *(short8*)(&Bs[n * LDA + c * 8]) = v;
        }
        __syncthreads();
        #pragma unroll
        for (int kk = 0; kk < 2; ++kk) {
            short8 af[4], bf[4];
            #pragma unroll
            for (int i = 0; i < 4; ++i)
                af[i] = *(const short8*)(&As[(wm * 64 + i * 16 + fr) * LDA + kk * 32 + fk]);
            #pragma unroll
            for (int j = 0; j < 4; ++j)
                bf[j] = *(const short8*)(&Bs[(wn * 64 + j * 16 + fr) * LDA + kk * 32 + fk]);
            #pragma unroll
            for (int i = 0; i < 4; ++i)
                #pragma unroll
                for (int j = 0; j < 4; ++j)
                    acc[i][j] = __builtin_amdgcn_mfma_f32_16x16x32_bf16(af[i], bf[j], acc[i][j], 0, 0, 0);
        }
        __syncthreads();
    }

    const int crow = row0 + wm * 64;
    const int ccol = col0 + wn * 64;
    #pragma unroll
    for (int i = 0; i < 4; ++i) {
        #pragma unroll
        for (int j = 0; j < 4; ++j) {
            int col = ccol + j * 16 + (lane & 15);
            float bv = bias ? bias[col] : 0.0f;
            #pragma unroll
            for (int reg = 0; reg < 4; ++reg) {
                int r = crow + i * 16 + (lane >> 4) * 4 + reg;
                if (r < M) {
                    float v = acc[i][j][reg] + bv;
                    if (ACT == 1) v = (v > 0.0f) ? v : expm1f(v);
                    C[(size_t)r * N + col] = (OutT)v;
                }
            }
        }
    }
}

// ---------------------------------------------------------------------------
// Dispatch F: fused GATv2 layer 1 (VERIFIED 147µs config: 1-deep prefetch,
// branchy exp2 online softmax, f32x2 pk arithmetic, 32 VGPR).
// xlr bf16 [N,1024]: 0..511 xl, 512..1023 xr.
// ---------------------------------------------------------------------------
__global__ __launch_bounds__(256) void gatv2_l1_fused_kernel(
    const __hip_bfloat16* __restrict__ xlr,
    const int* __restrict__ row, const int* __restrict__ src_sorted,
    const float* __restrict__ att, const float* __restrict__ b1,
    __hip_bfloat16* __restrict__ out1, int N)
{
    int d = blockIdx.x * 4 + (threadIdx.x >> 6);
    if (d >= N) return;
    int lane = threadIdx.x & 63;
    int cbase = lane * 8;
    const short* basep = (const short*)xlr;

    f32x2 xrd2[4], attv2[4];
    {
        uint4 raw = *reinterpret_cast<const uint4*>(basep + (size_t)d * 1024 + 512 + cbase);
        const unsigned* u = reinterpret_cast<const unsigned*>(&raw);
        #pragma unroll
        for (int j = 0; j < 4; ++j) xrd2[j] = unpack2(u[j]);
        #pragma unroll
        for (int j = 0; j < 4; ++j) {
            attv2[j].x = att[cbase + 2 * j] * LOG2E;
            attv2[j].y = att[cbase + 2 * j + 1] * LOG2E;
        }
    }

    float m = MNEG;
    float s = 0.0f;
    f32x2 o2[4] = {};

    int rs = row[d], re = row[d + 1];

    uint4 raw = *reinterpret_cast<const uint4*>(basep + (size_t)d * 1024 + cbase);
    for (int it = rs - 1; it < re; ++it) {
        uint4 cur = raw;
        if (it + 1 < re) {
            int sn = src_sorted[it + 1];
            raw = *reinterpret_cast<const uint4*>(basep + (size_t)sn * 1024 + cbase);
        }
        const unsigned* u = reinterpret_cast<const unsigned*>(&cur);
        f32x2 v2[4];
        #pragma unroll
        for (int j = 0; j < 4; ++j) v2[j] = unpack2(u[j]);

        f32x2 tacc = {0.0f, 0.0f};
        #pragma unroll
        for (int j = 0; j < 4; ++j) {
            f32x2 e = v2[j] + xrd2[j];
            f32x2 ne = e * NEG_SLOPE;
            e.x = fmaxf(e.x, ne.x);
            e.y = fmaxf(e.y, ne.y);
            tacc = __builtin_elementwise_fma(e, attv2[j], tacc);
        }
        float t = tacc.x + tacc.y;
        t += __shfl_xor(t, 1);
        t += __shfl_xor(t, 2);
        t += __shfl_xor(t, 4);
        t += __shfl_xor(t, 8);
        if (t > m) {
            float r = exp2f(m - t);
            s *= r;
            f32x2 r2 = {r, r};
            #pragma unroll
            for (int j = 0; j < 4; ++j) o2[j] *= r2;
            m = t;
        }
        float p = exp2f(t - m);
        s += p;
        f32x2 p2 = {p, p};
        #pragma unroll
        for (int j = 0; j < 4; ++j) o2[j] = __builtin_elementwise_fma(p2, v2[j], o2[j]);
    }

    float inv = 1.0f / (s + 1e-16f);
    short8 sv;
    #pragma unroll
    for (int j = 0; j < 4; ++j) {
        #pragma unroll
        for (int h = 0; h < 2; ++h) {
            float val = ((h == 0) ? o2[j].x : o2[j].y) * inv + b1[cbase + 2 * j + h];
            val = (val > 0.0f) ? val : expm1f(val);
            __hip_bfloat16 hb = __float2bfloat16(val);
            sv[2 * j + h] = *reinterpret_cast<short*>(&hb);
        }
    }
    *(short8*)((short*)out1 + (size_t)d * HC1 + cbase) = sv;
}

// ---------------------------------------------------------------------------
// Dispatch H: fused GATv2 layer 2 + classifier + log_softmax (verified r13).
// ---------------------------------------------------------------------------
__global__ __launch_bounds__(256) void gatv2_l2_final_kernel(
    const __hip_bfloat16* __restrict__ xlr2,
    const int* __restrict__ row, const int* __restrict__ src_sorted,
    const float* __restrict__ att2, const float* __restrict__ b2,
    const float* __restrict__ w_out, const float* __restrict__ b_out,
    float* __restrict__ out, int N)
{
    int d = blockIdx.x * 4 + (threadIdx.x >> 6);
    if (d >= N) return;
    int lane = threadIdx.x & 63;
    int g  = lane >> 4;
    int gl = lane & 15;
    int cbase = gl * 8;
    const short* basep = (const short*)xlr2;

    f32x2 xrd2[4], attv2[4];
    {
        uint4 rawx = *reinterpret_cast<const uint4*>(basep + (size_t)d * 256 + 128 + cbase);
        const unsigned* u = reinterpret_cast<const unsigned*>(&rawx);
        #pragma unroll
        for (int j = 0; j < 4; ++j) xrd2[j] = unpack2(u[j]);
        #pragma unroll
        for (int j = 0; j < 4; ++j) {
            attv2[j].x = att2[cbase + 2 * j] * LOG2E;
            attv2[j].y = att2[cbase + 2 * j + 1] * LOG2E;
        }
    }

    float m = MNEG;
    float s = 0.0f;
    f32x2 o2[4] = {};

    int rs = row[d], re = row[d + 1];
    int L = re - rs + 1;

    uint4 r0;
    if (g < L) {
        int sn = (g == 0) ? d : src_sorted[rs + g - 1];
        r0 = *reinterpret_cast<const uint4*>(basep + (size_t)sn * 256 + cbase);
    }
    for (int p0 = g; p0 < L; p0 += 4) {
        uint4 cur = r0;
        if (p0 + 4 < L) {
            int sn = src_sorted[rs + p0 + 3];
            r0 = *reinterpret_cast<const uint4*>(basep + (size_t)sn * 256 + cbase);
        }
        const unsigned* u = reinterpret_cast<const unsigned*>(&cur);
        f32x2 v2[4];
        #pragma unroll
        for (int j = 0; j < 4; ++j) v2[j] = unpack2(u[j]);

        f32x2 tacc = {0.0f, 0.0f};
        #pragma unroll
        for (int j = 0; j < 4; ++j) {
            f32x2 e = v2[j] + xrd2[j];
            f32x2 ne = e * NEG_SLOPE;
            e.x = fmaxf(e.x, ne.x);
            e.y = fmaxf(e.y, ne.y);
            tacc = __builtin_elementwise_fma(e, attv2[j], tacc);
        }
        float t = tacc.x + tacc.y;
        t += __shfl_xor(t, 1);
        t += __shfl_xor(t, 2);
        t += __shfl_xor(t, 4);
        t += __shfl_xor(t, 8);
        if (t > m) {
            float r = exp2f(m - t);
            s *= r;
            f32x2 r2 = {r, r};
            #pragma unroll
            for (int j = 0; j < 4; ++j) o2[j] *= r2;
            m = t;
        }
        float p = exp2f(t - m);
        s += p;
        f32x2 p2 = {p, p};
        #pragma unroll
        for (int j = 0; j < 4; ++j) o2[j] = __builtin_elementwise_fma(p2, v2[j], o2[j]);
    }

    #pragma unroll
    for (int off = 16; off <= 32; off <<= 1) {
        float m_o = __shfl_xor(m, off);
        float s_o = __shfl_xor(s, off);
        f32x2 oo[4];
        #pragma unroll
        for (int j = 0; j < 4; ++j) {
            oo[j].x = __shfl_xor(o2[j].x, off);
            oo[j].y = __shfl_xor(o2[j].y, off);
        }
        float mn = fmaxf(m, m_o);
        float a = exp2f(m - mn);
        float b = exp2f(m_o - mn);
        s = s * a + s_o * b;
        f32x2 a2 = {a, a}, b2v = {b, b};
        #pragma unroll
        for (int j = 0; j < 4; ++j)
            o2[j] = o2[j] * a2 + oo[j] * b2v;
        m = mn;
    }

    float inv = 1.0f / (s + 1e-16f);
    float a0 = 0.0f, a1 = 0.0f;
    #pragma unroll
    for (int j = 0; j < 4; ++j) {
        #pragma unroll
        for (int h = 0; h < 2; ++h) {
            int c = cbase + 2 * j + h;
            float val = ((h == 0) ? o2[j].x : o2[j].y) * inv + b2[c];
            val = (val > 0.0f) ? val : expm1f(val);
            a0 = fmaf(val, w_out[c * 2 + 0], a0);
            a1 = fmaf(val, w_out[c * 2 + 1], a1);
        }
    }
    #pragma unroll
    for (int off = 1; off <= 8; off <<= 1) {
        a0 += __shfl_xor(a0, off);
        a1 += __shfl_xor(a1, off);
    }
    if (lane == 0) {
        float z0 = a0 + b_out[0];
        float z1 = a1 + b_out[1];
        float mx = fmaxf(z0, z1);
        float lse = mx + logf(__expf(z0 - mx) + __expf(z1 - mx));
        out[(size_t)d * CLASSES + 0] = z0 - lse;
        out[(size_t)d * CLASSES + 1] = z1 - lse;
    }
}

// ---------------------------------------------------------------------------
// launch — 8 dispatches
// ---------------------------------------------------------------------------
extern "C" void kernel_launch(void* const* d_in, const int* in_sizes, int n_in,
                              void* d_out, int out_size, void* d_ws, size_t ws_size,
                              hipStream_t stream)
{
    const float* x     = (const float*)d_in[0];
    const int*   eidx  = (const int*)d_in[1];
    const float* w_in  = (const float*)d_in[2];
    const float* b_in  = (const float*)d_in[3];
    const float* wl1   = (const float*)d_in[4];
    const float* wr1   = (const float*)d_in[5];
    const float* att1  = (const float*)d_in[6];
    const float* b1    = (const float*)d_in[7];
    const float* wl2   = (const float*)d_in[8];
    const float* wr2   = (const float*)d_in[9];
    const float* att2  = (const float*)d_in[10];
    const float* b2    = (const float*)d_in[11];
    const float* w_out = (const float*)d_in[12];
    const float* b_out = (const float*)d_in[13];
    float* out = (float*)d_out;

    const int N = in_sizes[0] / F_IN;      // 50000
    const int E = in_sizes[1] / 2;         // 800000
    const int* src_arr = eidx;
    const int* dst_arr = eidx + E;

    // ---- workspace layout (peak ~160 MB) ----
    size_t off = 0;
    auto alloc = [&](size_t bytes) -> char* {
        char* ptr = (char*)d_ws + off;
        off += (bytes + 255) & ~(size_t)255;
        return ptr;
    };
    int* row        = (int*)alloc((size_t)(N + 1) * 4);
    int* cursor     = (int*)alloc((size_t)N * 4);
    int* deg        = (int*)alloc((size_t)N * 4);
    int* src_sorted = (int*)alloc((size_t)E * 4);
    __hip_bfloat16* w_inT = (__hip_bfloat16*)alloc((size_t)F_IN * HID * 2);
    __hip_bfloat16* wT1   = (__hip_bfloat16*)alloc((size_t)2 * HC1 * HID * 2);  // [1024][128]
    __hip_bfloat16* wT2   = (__hip_bfloat16*)alloc((size_t)2 * HID * HC1 * 2);  // [256][512]
    __hip_bfloat16* xlr1  = (__hip_bfloat16*)alloc((size_t)N * 2 * HC1 * 2);    // [N][1024]
    __hip_bfloat16* out1  = (__hip_bfloat16*)alloc((size_t)N * HC1 * 2);

    __hip_bfloat16* xlr2 = xlr1;   // [N][256] overlays xlr1 (dead after fused L1)

    dim3 blk(256);
    const int NB_SCAN = (N + SCAN_CHUNK - 1) / SCAN_CHUNK;   // 25
    const int nRowBlk = (N + 127) / 128;                     // 391

    // A: weights prep ∥ zero(deg)
    hipLaunchKernelGGL(kA_prep_zero, dim3(PREP_BLOCKS + ZERO_BLOCKS), blk, 0, stream,
                       w_in, wl1, wr1, wl2, wr2, w_inT, wT1, wT2, deg, N);
    // B: deg histogram
    hipLaunchKernelGGL(deg_kernel, dim3((E + 255) / 256), blk, 0, stream, dst_arr, deg, E, N);
    // C: single-kernel scan
    hipLaunchKernelGGL(scan_kernel, dim3(NB_SCAN), blk, 0, stream, deg, row, cursor, N);
    // D: scatter
    hipLaunchKernelGGL(scatter_kernel, dim3((E + 255) / 256), blk, 0, stream,
                       src_arr, dst_arr, cursor, src_sorted, E, N);
    // E: merged input+L1 transform
    {
        dim3 grid(2, nRowBlk);
        hipLaunchKernelGGL(l1_merged_kernel, grid, blk, 0, stream,
                           x, w_inT, b_in, wT1, xlr1, N);
    }
    // F: fused layer 1 (verified 1-deep prefetch)
    hipLaunchKernelGGL(gatv2_l1_fused_kernel, dim3((N + 3) / 4), blk, 0, stream,
                       xlr1, row, src_sorted, att1, b1, out1, N);
    // G: layer 2 transform
    {
        dim3 grid(2 * HID / 128, nRowBlk);
        hipLaunchKernelGGL((mfma_gemm_kernel<0, __hip_bfloat16>), grid, blk, 0, stream,
                           out1, wT2, (const float*)nullptr, xlr2, N, HC1, 2 * HID);
    }
    // H: fused layer 2 + classifier + log_softmax
    hipLaunchKernelGGL(gatv2_l2_final_kernel, dim3((N + 3) / 4), blk, 0, stream,
                       xlr2, row, src_sorted, att2, b2, w_out, b_out, out, N);
}